// Round 2
// baseline (531.135 us; speedup 1.0000x reference)
//
#include <hip/hip_runtime.h>

typedef __bf16 bf16_t;
typedef __bf16 bf16x8 __attribute__((ext_vector_type(8)));
typedef __bf16 bf16x4 __attribute__((ext_vector_type(4)));
typedef float f32x4 __attribute__((ext_vector_type(4)));

#define SEQL 2048
#define DIMM 4096
#define NH 32
#define NKV 8
#define HD 128

__device__ __forceinline__ void gl2lds16(const void* g, void* l) {
  __builtin_amdgcn_global_load_lds((__attribute__((address_space(1))) void*)g,
                                   (__attribute__((address_space(3))) void*)l,
                                   16, 0, 0);
}

// ---------------- fused fp32 -> bf16 convert of all 5 tensors ----------------
__global__ __launch_bounds__(256) void cvt5_kernel(const float* __restrict__ s0,
                                                   const float* __restrict__ s1,
                                                   const float* __restrict__ s2,
                                                   const float* __restrict__ s3,
                                                   const float* __restrict__ s4,
                                                   bf16_t* __restrict__ dst) {
  const long base = (long)blockIdx.x * 4096;
  const float* s;
  long o;
  if (base < 8388608L)       { s = s0; o = base; }
  else if (base < 25165824L) { s = s1; o = base - 8388608L; }
  else if (base < 29360128L) { s = s2; o = base - 25165824L; }
  else if (base < 33554432L) { s = s3; o = base - 29360128L; }
  else                       { s = s4; o = base - 33554432L; }
  const long t4 = threadIdx.x * 4;
#pragma unroll
  for (int j = 0; j < 4; ++j) {
    const long e = t4 + j * 1024;
    float4 v = *(const float4*)(s + o + e);
    bf16x4 ov;
    ov[0] = (bf16_t)v.x; ov[1] = (bf16_t)v.y; ov[2] = (bf16_t)v.z; ov[3] = (bf16_t)v.w;
    *(bf16x4*)(dst + base + e) = ov;
  }
}

// ---------------- QKV GEMM, 256x256 tile, 8-wave deep-pipelined schedule -----
// BK=32, 4-slot LDS ring (128 KiB). Per tile: 2 phases, each {ds_read frags |
// stage 2 x global_load_lds for tile t+2 | barrier | lgkmcnt(0) | 16 MFMA |
// barrier}; one counted s_waitcnt vmcnt(4) per tile (never 0 in main loop).
// Epilogue: fused RMSNorm+RoPE (Q/K) or transposed write (V), per 128-row half.
#define BK2 32
#define EPS 264
#define QSCALE (0.08838834764831845f * 1.4426950408889634f)
__global__ __launch_bounds__(512, 2) void gemm_qkv8(const bf16_t* __restrict__ A,
                                                    const bf16_t* __restrict__ B,
                                                    const float* __restrict__ qnw,
                                                    const float* __restrict__ knw,
                                                    const float* __restrict__ rope,
                                                    const int* __restrict__ pos,
                                                    bf16_t* __restrict__ Qb,
                                                    bf16_t* __restrict__ Kb,
                                                    bf16_t* __restrict__ Vb) {
  // A ring: 4 slots x [256][32] bf16 at smem+slot*8192
  // B ring: 4 slots x [256][32] bf16 at smem+32768+slot*8192   (total 128 KiB)
  __shared__ __align__(16) bf16_t smem[65536];
  const int K = DIMM;
  const int NT = K / BK2;  // 128 K-tiles
  const int tid = threadIdx.x;
  const int lin = blockIdx.x;            // 192 blocks: 8 m-tiles x 24 n-tiles
  const int xcd = lin & 7, idx = lin >> 3;
  const int bm = (idx & 7) * 256;
  const int bn = ((idx >> 3) + xcd * 3) * 256;  // 3 n-panels per XCD
  const int lane = tid & 63, wave = tid >> 6;
  const int wrow = wave >> 2, wcol = wave & 3;  // 2(M) x 4(N) waves
  const int wm = wrow * 128, wn = wcol * 64;    // per-wave 128x64 output
  const int lr = lane & 15, quad = lane >> 4;
  const int swz = (quad ^ ((lr >> 1) & 3)) << 3;  // read-side slot swizzle

  // staging: chunk id in [0,1024): row=id>>2, dest slot=id&3 (linear LDS dest),
  // source k pre-swizzled so that read-side XOR recovers k=quad*8+e.
  long asrc[2]; int adst[2];
#pragma unroll
  for (int c = 0; c < 2; ++c) {
    const int id = tid + 512 * c;
    asrc[c] = (long)(id >> 2) * K + (long)((((id & 3) ^ ((id >> 3) & 3)) << 3));
    adst[c] = id * 8;
  }
  const bf16_t* Abase = A + (long)bm * K;
  const bf16_t* Bbase = B + (long)bn * K;

  f32x4 acc[8][4];
#pragma unroll
  for (int mi = 0; mi < 8; ++mi)
#pragma unroll
    for (int ni = 0; ni < 4; ++ni)
      acc[mi][ni] = (f32x4){0.f, 0.f, 0.f, 0.f};

#define STAGE(t, c)                                                              \
  do {                                                                           \
    const int slot_ = (t) & 3;                                                   \
    const long k0_ = (long)(t) * BK2;                                            \
    gl2lds16(Abase + asrc[c] + k0_, smem + slot_ * 8192 + adst[c]);              \
    gl2lds16(Bbase + asrc[c] + k0_, smem + 32768 + slot_ * 8192 + adst[c]);      \
  } while (0)

  // prologue: tiles 0 and 1 in flight; wait tile 0 only (tile 1 stays flying)
  STAGE(0, 0); STAGE(0, 1); STAGE(1, 0); STAGE(1, 1);
  asm volatile("s_waitcnt vmcnt(4)" ::: "memory");
  __builtin_amdgcn_s_barrier();

  for (int t = 0; t < NT; ++t) {
    const bf16_t* As = smem + (t & 3) * 8192;
    const bf16_t* Bs = smem + 32768 + (t & 3) * 8192;
    bf16x8 af[4], bfr[4];
    // ---- phase A: m-half 0, all 4 n-frags ----
#pragma unroll
    for (int mi = 0; mi < 4; ++mi)
      af[mi] = *(const bf16x8*)&As[(wm + mi * 16 + lr) * 32 + swz];
#pragma unroll
    for (int ni = 0; ni < 4; ++ni)
      bfr[ni] = *(const bf16x8*)&Bs[(wn + ni * 16 + lr) * 32 + swz];
    if (t + 2 < NT) STAGE(t + 2, 0);
    __builtin_amdgcn_s_barrier();
    asm volatile("s_waitcnt lgkmcnt(0)" ::: "memory");
    __builtin_amdgcn_sched_barrier(0);
    __builtin_amdgcn_s_setprio(1);
#pragma unroll
    for (int mi = 0; mi < 4; ++mi)
#pragma unroll
      for (int ni = 0; ni < 4; ++ni)
        acc[mi][ni] = __builtin_amdgcn_mfma_f32_16x16x32_bf16(af[mi], bfr[ni], acc[mi][ni], 0, 0, 0);
    __builtin_amdgcn_s_setprio(0);
    __builtin_amdgcn_s_barrier();
    // ---- phase B: m-half 1, reuse B frags ----
#pragma unroll
    for (int mi = 0; mi < 4; ++mi)
      af[mi] = *(const bf16x8*)&As[(wm + 64 + mi * 16 + lr) * 32 + swz];
    if (t + 2 < NT) STAGE(t + 2, 1);
    __builtin_amdgcn_s_barrier();
    asm volatile("s_waitcnt lgkmcnt(0)" ::: "memory");
    __builtin_amdgcn_sched_barrier(0);
    __builtin_amdgcn_s_setprio(1);
#pragma unroll
    for (int mi = 0; mi < 4; ++mi)
#pragma unroll
      for (int ni = 0; ni < 4; ++ni)
        acc[4 + mi][ni] = __builtin_amdgcn_mfma_f32_16x16x32_bf16(af[mi], bfr[ni], acc[4 + mi][ni], 0, 0, 0);
    __builtin_amdgcn_s_setprio(0);
    // counted wait: ensures tile t+1 landed; leaves tile t+2's 4 loads in flight
    if (t + 2 < NT) { asm volatile("s_waitcnt vmcnt(4)" ::: "memory"); }
    else            { asm volatile("s_waitcnt vmcnt(0)" ::: "memory"); }
    __builtin_amdgcn_s_barrier();
  }
#undef STAGE

  // ---- epilogue: two 128-row halves through LDS (stride EPS) ----
  const bool isQ = bn < 4096;
  const bool isV = bn >= 5120;
#pragma unroll 1
  for (int half = 0; half < 2; ++half) {
    __syncthreads();
    if (wrow == half) {
#pragma unroll
      for (int mi = 0; mi < 8; ++mi)
#pragma unroll
        for (int ni = 0; ni < 4; ++ni)
#pragma unroll
          for (int r = 0; r < 4; ++r)
            smem[(mi * 16 + quad * 4 + r) * EPS + wn + ni * 16 + lr] = (bf16_t)acc[mi][ni][r];
    }
    __syncthreads();
    const int growb = bm + half * 128;
    if (!isV) {  // ---- Q or K heads: RMSNorm + RoPE, write [h][s][128] ----
      const int r = tid >> 2, hh = (tid >> 1) & 1, hf = tid & 1;
      const int cb = bn + hh * 128;
      const float* nwp = isQ ? qnw : knw;
      const float osc = isQ ? QSCALE : 1.0f;
      bf16_t* outp = isQ ? (Qb + (long)(cb >> 7) * SEQL * HD)
                         : (Kb + (long)((cb - 4096) >> 7) * SEQL * HD);
      bf16x8 rowv[16];
#pragma unroll
      for (int j = 0; j < 16; ++j) rowv[j] = *(const bf16x8*)&smem[r * EPS + hh * 128 + j * 8];
      float ss = 0.f;
#pragma unroll
      for (int j = 0; j < 16; ++j)
#pragma unroll
        for (int e = 0; e < 8; ++e) { const float f = (float)rowv[j][e]; ss += f * f; }
      const float sc = rsqrtf(ss * (1.0f / 128.0f) + 1e-6f) * osc;
      const int p = pos[growb + r];
      const float* rp = rope + p * 128;
      bf16_t obuf[64];
#pragma unroll
      for (int g = 0; g < 8; ++g) {
#pragma unroll
        for (int e = 0; e < 8; ++e) {
          const int i = g * 8 + e;
          const float2 cs = *(const float2*)(rp + 2 * i);
          const float nlo = (float)rowv[i >> 3][i & 7] * sc * nwp[i];
          const float nhi = (float)rowv[8 + (i >> 3)][i & 7] * sc * nwp[64 + i];
          obuf[i] = (bf16_t)(hf ? (nhi * cs.x + nlo * cs.y) : (nlo * cs.x - nhi * cs.y));
        }
      }
      bf16_t* op = outp + (long)(growb + r) * HD + hf * 64;
#pragma unroll
      for (int g = 0; g < 8; ++g) *(bf16x8*)(op + g * 8) = *(const bf16x8*)&obuf[g * 8];
    } else {  // ---- V heads: transposed write [hk][d][s] ----
      const int d = tid & 127, q2 = tid >> 7;
      const int hh = q2 >> 1, shalf = q2 & 1;
      const int hv = ((bn - 5120) >> 7) + hh;
      bf16_t* vp = Vb + ((long)hv * HD + d) * SEQL + growb + shalf * 64;
#pragma unroll
      for (int grp = 0; grp < 8; ++grp) {
        bf16x8 tv;
#pragma unroll
        for (int e = 0; e < 8; ++e) tv[e] = smem[(shalf * 64 + grp * 8 + e) * EPS + hh * 128 + d];
        *(bf16x8*)(vp + grp * 8) = tv;
      }
    }
  }
}

// ---------------- plain NT GEMM (O-projection): C[M,N] = A @ B^T, fp32 out ---
template <typename CT>
__global__ __launch_bounds__(256, 3) void gemm_bt_kernel(const bf16_t* __restrict__ A,
                                                         const bf16_t* __restrict__ B,
                                                         CT* __restrict__ C,
                                                         int N, int K, int npanel) {
  __shared__ bf16_t lA[128 * 64];
  __shared__ bf16_t lB[128 * 64];
  const int tid = threadIdx.x;
  const int lin = blockIdx.x;
  const int xcd = lin & 7, idx = lin >> 3;
  const int bm = (idx & 15) * 128;
  const int bn = ((idx >> 4) + xcd * npanel) * 128;
  const int lane = tid & 63, wave = tid >> 6;
  const int wm = (wave >> 1) * 64, wn = (wave & 1) * 64;
  const int lr = lane & 15, quad = lane >> 4;

  f32x4 acc[4][4];
#pragma unroll
  for (int mi = 0; mi < 4; ++mi)
#pragma unroll
    for (int ni = 0; ni < 4; ++ni)
      acc[mi][ni] = (f32x4){0.f, 0.f, 0.f, 0.f};

  long soff[4];
#pragma unroll
  for (int c = 0; c < 4; ++c) {
    const int s = tid + 256 * c;
    soff[c] = (long)(s >> 3) * K + (((s & 7) ^ ((s >> 3) & 7)) << 3);
  }
  const bf16_t* Abase = A + (long)bm * K;
  const bf16_t* Bbase = B + (long)bn * K;

  for (int k0 = 0; k0 < K; k0 += 64) {
    __syncthreads();
#pragma unroll
    for (int c = 0; c < 4; ++c) {
      gl2lds16(Abase + soff[c] + k0, lA + (tid + 256 * c) * 8);
      gl2lds16(Bbase + soff[c] + k0, lB + (tid + 256 * c) * 8);
    }
    __syncthreads();
#pragma unroll
    for (int ks = 0; ks < 2; ++ks) {
      bf16x8 af[4], bfr[4];
#pragma unroll
      for (int mi = 0; mi < 4; ++mi)
        af[mi] = *(const bf16x8*)&lA[(wm + mi * 16 + lr) * 64 + ((((ks << 2) | quad) ^ (lr & 7)) << 3)];
#pragma unroll
      for (int ni = 0; ni < 4; ++ni)
        bfr[ni] = *(const bf16x8*)&lB[(wn + ni * 16 + lr) * 64 + ((((ks << 2) | quad) ^ (lr & 7)) << 3)];
#pragma unroll
      for (int mi = 0; mi < 4; ++mi)
#pragma unroll
        for (int ni = 0; ni < 4; ++ni)
          acc[mi][ni] = __builtin_amdgcn_mfma_f32_16x16x32_bf16(af[mi], bfr[ni], acc[mi][ni], 0, 0, 0);
    }
  }

#pragma unroll
  for (int mi = 0; mi < 4; ++mi) {
    const int row = bm + wm + mi * 16 + quad * 4;
#pragma unroll
    for (int ni = 0; ni < 4; ++ni) {
      const int col = bn + wn + ni * 16 + lr;
      CT* cp = C + (long)row * N + col;
#pragma unroll
      for (int r = 0; r < 4; ++r) cp[(long)r * N] = (CT)acc[mi][ni][r];
    }
  }
}

// ---------------- flash attention, block-diag causal, FIXED-RANGE softmax ----
#define CK 64
#define PSTR 72
__global__ __launch_bounds__(256) void attn_kernel(const bf16_t* __restrict__ Q,
                                                   const bf16_t* __restrict__ Kt,
                                                   const bf16_t* __restrict__ Vt,
                                                   bf16_t* __restrict__ O) {
  __shared__ bf16_t lK[CK * 128];    // [kk][d]
  __shared__ bf16_t lV[144 * CK];    // [d][kk]; rows 128..143 = ones (l trick)
  __shared__ bf16_t lP[128 * PSTR];  // [m][kk]
  const int lin = blockIdx.x;
  const int qb = (lin < 256) ? (3 - (lin & 1)) : (lin & 1);
  const int gh = (lin >> 1) & 127;
  const int h = gh & 31, g = gh >> 5;
  const int hk = h >> 2;
  const int tid = threadIdx.x, lane = tid & 63, wave = tid >> 6;
  const int lr = lane & 15, quad = lane >> 4;
  const int s_base = g * 512 + qb * 128;

  if (tid < 128) {
    bf16x8 one8;
#pragma unroll
    for (int j = 0; j < 8; ++j) one8[j] = (bf16_t)1.0f;
    *(bf16x8*)&lV[128 * CK + tid * 8] = one8;
  }

  bf16x8 qf[2][4];
  const bf16_t* Qp = Q + ((long)h * SEQL + s_base + wave * 32 + lr) * HD + quad * 8;
#pragma unroll
  for (int mi = 0; mi < 2; ++mi)
#pragma unroll
    for (int ks = 0; ks < 4; ++ks)
      qf[mi][ks] = *(const bf16x8*)(Qp + mi * 16 * HD + ks * 32);

  f32x4 oacc[2][9];
#pragma unroll
  for (int mi = 0; mi < 2; ++mi)
#pragma unroll
    for (int di = 0; di < 9; ++di) oacc[mi][di] = (f32x4){0.f, 0.f, 0.f, 0.f};

  const int nchunk = 2 * qb + 2;
  for (int c = 0; c < nchunk; ++c) {
    __syncthreads();
    {
      const bf16_t* Kg = Kt + ((long)hk * SEQL + g * 512 + c * CK) * HD;
      const bf16_t* Vg = Vt + (long)hk * HD * SEQL + g * 512 + c * CK;
#pragma unroll
      for (int cc = 0; cc < 4; ++cc) {
        const int i = tid + 256 * cc;
        gl2lds16(Kg + (long)(i >> 4) * HD + (i & 15) * 8, lK + i * 8);
        gl2lds16(Vg + (long)(i >> 3) * SEQL + (i & 7) * 8, lV + i * 8);
      }
    }
    __syncthreads();

    f32x4 sv[2][4];
#pragma unroll
    for (int mi = 0; mi < 2; ++mi)
#pragma unroll
      for (int ni = 0; ni < 4; ++ni) sv[mi][ni] = (f32x4){0.f, 0.f, 0.f, 0.f};
#pragma unroll
    for (int ks = 0; ks < 4; ++ks) {
#pragma unroll
      for (int ni = 0; ni < 4; ++ni) {
        const bf16x8 kf = *(const bf16x8*)&lK[(ni * 16 + lr) * 128 + ks * 32 + quad * 8];
        sv[0][ni] = __builtin_amdgcn_mfma_f32_16x16x32_bf16(qf[0][ks], kf, sv[0][ni], 0, 0, 0);
        sv[1][ni] = __builtin_amdgcn_mfma_f32_16x16x32_bf16(qf[1][ks], kf, sv[1][ni], 0, 0, 0);
      }
    }

#pragma unroll
    for (int mi = 0; mi < 2; ++mi)
#pragma unroll
      for (int ni = 0; ni < 4; ++ni)
#pragma unroll
        for (int r = 0; r < 4; ++r) {
          const int colseg = c * CK + ni * 16 + lr;
          const int rowseg = qb * 128 + wave * 32 + mi * 16 + quad * 4 + r;
          float p = exp2f(sv[mi][ni][r]);
          p = (colseg > rowseg) ? 0.f : p;
          lP[(wave * 32 + mi * 16 + quad * 4 + r) * PSTR + ni * 16 + lr] = (bf16_t)p;
        }
    __syncthreads();

#pragma unroll
    for (int ks = 0; ks < 2; ++ks) {
      const bf16x8 pf0 = *(const bf16x8*)&lP[(wave * 32 + lr) * PSTR + ks * 32 + quad * 8];
      const bf16x8 pf1 = *(const bf16x8*)&lP[(wave * 32 + 16 + lr) * PSTR + ks * 32 + quad * 8];
#pragma unroll
      for (int di = 0; di < 9; ++di) {
        const bf16x8 vfr = *(const bf16x8*)&lV[(di * 16 + lr) * CK + ks * 32 + quad * 8];
        oacc[0][di] = __builtin_amdgcn_mfma_f32_16x16x32_bf16(pf0, vfr, oacc[0][di], 0, 0, 0);
        oacc[1][di] = __builtin_amdgcn_mfma_f32_16x16x32_bf16(pf1, vfr, oacc[1][di], 0, 0, 0);
      }
    }
  }

#pragma unroll
  for (int mi = 0; mi < 2; ++mi)
#pragma unroll
    for (int r = 0; r < 4; ++r) {
      const float inv = 1.0f / oacc[mi][8][r];
      const int row = s_base + wave * 32 + mi * 16 + quad * 4 + r;
      bf16_t* opp = O + (long)row * DIMM + h * HD + lr;
#pragma unroll
      for (int di = 0; di < 8; ++di) opp[di * 16] = (bf16_t)(oacc[mi][di][r] * inv);
    }
}

// -----------------------------------------------------------------------------
extern "C" void kernel_launch(void* const* d_in, const int* in_sizes, int n_in,
                              void* d_out, int out_size, void* d_ws, size_t ws_size,
                              hipStream_t stream) {
  (void)in_sizes; (void)n_in; (void)out_size; (void)ws_size;
  const float* x    = (const float*)d_in[0];
  const float* wq   = (const float*)d_in[1];
  const float* wk   = (const float*)d_in[2];
  const float* wv   = (const float*)d_in[3];
  const float* wo   = (const float*)d_in[4];
  const float* qnw  = (const float*)d_in[5];
  const float* knw  = (const float*)d_in[6];
  const float* rope = (const float*)d_in[7];
  const int*   pos  = (const int*)d_in[8];
  float* out = (float*)d_out;

  char* ws = (char*)d_ws;
  size_t off = 0;
  auto alloc = [&](size_t b) { char* p = ws + off; off += (b + 255) & ~(size_t)255; return p; };
  bf16_t* xb    = (bf16_t*)alloc((size_t)SEQL * DIMM * 2);
  bf16_t* wqkvb = (bf16_t*)alloc((size_t)DIMM * DIMM * 2);
  alloc((size_t)NKV * HD * DIMM * 2);
  alloc((size_t)NKV * HD * DIMM * 2);
  bf16_t* wob   = (bf16_t*)alloc((size_t)DIMM * DIMM * 2);
  bf16_t* Qb    = (bf16_t*)alloc((size_t)NH * SEQL * HD * 2);
  bf16_t* Kb    = (bf16_t*)alloc((size_t)NKV * SEQL * HD * 2);
  bf16_t* Vb    = (bf16_t*)alloc((size_t)NKV * SEQL * HD * 2);
  bf16_t* attnb = xb;  // xb dead after QKV GEMM

  cvt5_kernel<<<dim3(12288), 256, 0, stream>>>(x, wq, wk, wv, wo, xb);
  gemm_qkv8<<<dim3(192), 512, 0, stream>>>(xb, wqkvb, qnw, knw, rope, pos, Qb, Kb, Vb);
  attn_kernel<<<dim3(512), 256, 0, stream>>>(Qb, Kb, Vb, attnb);
  gemm_bt_kernel<float><<<dim3(512), 256, 0, stream>>>(attnb, wob, out, DIMM, DIMM, 4);
}

// Round 3
// 525.360 us; speedup vs baseline: 1.0110x; 1.0110x over previous
//
#include <hip/hip_runtime.h>

typedef __bf16 bf16_t;
typedef __bf16 bf16x8 __attribute__((ext_vector_type(8)));
typedef __bf16 bf16x4 __attribute__((ext_vector_type(4)));
typedef float f32x4 __attribute__((ext_vector_type(4)));

#define SEQL 2048
#define DIMM 4096
#define NH 32
#define NKV 8
#define HD 128

__device__ __forceinline__ void gl2lds16(const void* g, void* l) {
  __builtin_amdgcn_global_load_lds((__attribute__((address_space(1))) void*)g,
                                   (__attribute__((address_space(3))) void*)l,
                                   16, 0, 0);
}

// ---------------- fused fp32 -> bf16 convert of all 5 tensors ----------------
__global__ __launch_bounds__(256) void cvt5_kernel(const float* __restrict__ s0,
                                                   const float* __restrict__ s1,
                                                   const float* __restrict__ s2,
                                                   const float* __restrict__ s3,
                                                   const float* __restrict__ s4,
                                                   bf16_t* __restrict__ dst) {
  const long base = (long)blockIdx.x * 4096;
  const float* s;
  long o;
  if (base < 8388608L)       { s = s0; o = base; }
  else if (base < 25165824L) { s = s1; o = base - 8388608L; }
  else if (base < 29360128L) { s = s2; o = base - 25165824L; }
  else if (base < 33554432L) { s = s3; o = base - 29360128L; }
  else                       { s = s4; o = base - 33554432L; }
  const long t4 = threadIdx.x * 4;
#pragma unroll
  for (int j = 0; j < 4; ++j) {
    const long e = t4 + j * 1024;
    float4 v = *(const float4*)(s + o + e);
    bf16x4 ov;
    ov[0] = (bf16_t)v.x; ov[1] = (bf16_t)v.y; ov[2] = (bf16_t)v.z; ov[3] = (bf16_t)v.w;
    *(bf16x4*)(dst + base + e) = ov;
  }
}

// ---------------- QKV GEMM, 256x256 tile, 8-wave deep-pipelined schedule -----
// BK=32, 4-slot LDS ring (128 KiB). Per tile: 2 phases, each {ds_read frags |
// stage 2 x global_load_lds for tile t+2 | barrier | lgkmcnt(0) | 16 MFMA |
// barrier}; one counted s_waitcnt vmcnt(4) per tile (never 0 in main loop).
// launch_bounds (512,1): 1 block/CU (LDS enforces this anyway) -> 256-VGPR cap.
// (512,2) capped at 128 VGPR and spilled the 128-VGPR accumulator: round-2
// showed WRITE_SIZE +45MB scratch, MfmaUtil 20%.
#define BK2 32
#define EPS 264
#define QSCALE (0.08838834764831845f * 1.4426950408889634f)
__global__ __launch_bounds__(512, 1) void gemm_qkv8(const bf16_t* __restrict__ A,
                                                    const bf16_t* __restrict__ B,
                                                    const float* __restrict__ qnw,
                                                    const float* __restrict__ knw,
                                                    const float* __restrict__ rope,
                                                    const int* __restrict__ pos,
                                                    bf16_t* __restrict__ Qb,
                                                    bf16_t* __restrict__ Kb,
                                                    bf16_t* __restrict__ Vb) {
  // A ring: 4 slots x [256][32] bf16 at smem+slot*8192
  // B ring: 4 slots x [256][32] bf16 at smem+32768+slot*8192   (total 128 KiB)
  __shared__ __align__(16) bf16_t smem[65536];
  const int K = DIMM;
  const int NT = K / BK2;  // 128 K-tiles
  const int tid = threadIdx.x;
  const int lin = blockIdx.x;            // 192 blocks: 8 m-tiles x 24 n-tiles
  const int xcd = lin & 7, idx = lin >> 3;
  const int bm = (idx & 7) * 256;
  const int bn = ((idx >> 3) + xcd * 3) * 256;  // 3 n-panels per XCD
  const int lane = tid & 63, wave = tid >> 6;
  const int wrow = wave >> 2, wcol = wave & 3;  // 2(M) x 4(N) waves
  const int wm = wrow * 128, wn = wcol * 64;    // per-wave 128x64 output
  const int lr = lane & 15, quad = lane >> 4;
  const int swz = (quad ^ ((lr >> 1) & 3)) << 3;  // read-side slot swizzle

  // staging: chunk id in [0,1024): row=id>>2, dest slot=id&3 (linear LDS dest),
  // source k pre-swizzled so that read-side XOR recovers k=quad*8+e.
  long asrc[2]; int adst[2];
#pragma unroll
  for (int c = 0; c < 2; ++c) {
    const int id = tid + 512 * c;
    asrc[c] = (long)(id >> 2) * K + (long)((((id & 3) ^ ((id >> 3) & 3)) << 3));
    adst[c] = id * 8;
  }
  const bf16_t* Abase = A + (long)bm * K;
  const bf16_t* Bbase = B + (long)bn * K;

  f32x4 acc[8][4];
#pragma unroll
  for (int mi = 0; mi < 8; ++mi)
#pragma unroll
    for (int ni = 0; ni < 4; ++ni)
      acc[mi][ni] = (f32x4){0.f, 0.f, 0.f, 0.f};

#define STAGE(t, c)                                                              \
  do {                                                                           \
    const int slot_ = (t) & 3;                                                   \
    const long k0_ = (long)(t) * BK2;                                            \
    gl2lds16(Abase + asrc[c] + k0_, smem + slot_ * 8192 + adst[c]);              \
    gl2lds16(Bbase + asrc[c] + k0_, smem + 32768 + slot_ * 8192 + adst[c]);      \
  } while (0)

  // prologue: tiles 0 and 1 in flight; wait tile 0 only (tile 1 stays flying)
  STAGE(0, 0); STAGE(0, 1); STAGE(1, 0); STAGE(1, 1);
  asm volatile("s_waitcnt vmcnt(4)" ::: "memory");
  __builtin_amdgcn_s_barrier();

  for (int t = 0; t < NT; ++t) {
    const bf16_t* As = smem + (t & 3) * 8192;
    const bf16_t* Bs = smem + 32768 + (t & 3) * 8192;
    bf16x8 af[4], bfr[4];
    // ---- phase A: m-half 0, all 4 n-frags ----
#pragma unroll
    for (int mi = 0; mi < 4; ++mi)
      af[mi] = *(const bf16x8*)&As[(wm + mi * 16 + lr) * 32 + swz];
#pragma unroll
    for (int ni = 0; ni < 4; ++ni)
      bfr[ni] = *(const bf16x8*)&Bs[(wn + ni * 16 + lr) * 32 + swz];
    if (t + 2 < NT) STAGE(t + 2, 0);
    __builtin_amdgcn_s_barrier();
    asm volatile("s_waitcnt lgkmcnt(0)" ::: "memory");
    __builtin_amdgcn_sched_barrier(0);
    __builtin_amdgcn_s_setprio(1);
#pragma unroll
    for (int mi = 0; mi < 4; ++mi)
#pragma unroll
      for (int ni = 0; ni < 4; ++ni)
        acc[mi][ni] = __builtin_amdgcn_mfma_f32_16x16x32_bf16(af[mi], bfr[ni], acc[mi][ni], 0, 0, 0);
    __builtin_amdgcn_s_setprio(0);
    __builtin_amdgcn_s_barrier();
    // ---- phase B: m-half 1, reuse B frags ----
#pragma unroll
    for (int mi = 0; mi < 4; ++mi)
      af[mi] = *(const bf16x8*)&As[(wm + 64 + mi * 16 + lr) * 32 + swz];
    if (t + 2 < NT) STAGE(t + 2, 1);
    __builtin_amdgcn_s_barrier();
    asm volatile("s_waitcnt lgkmcnt(0)" ::: "memory");
    __builtin_amdgcn_sched_barrier(0);
    __builtin_amdgcn_s_setprio(1);
#pragma unroll
    for (int mi = 0; mi < 4; ++mi)
#pragma unroll
      for (int ni = 0; ni < 4; ++ni)
        acc[4 + mi][ni] = __builtin_amdgcn_mfma_f32_16x16x32_bf16(af[mi], bfr[ni], acc[4 + mi][ni], 0, 0, 0);
    __builtin_amdgcn_s_setprio(0);
    // counted wait: ensures tile t+1 landed; leaves tile t+2's 4 loads in flight
    if (t + 2 < NT) { asm volatile("s_waitcnt vmcnt(4)" ::: "memory"); }
    else            { asm volatile("s_waitcnt vmcnt(0)" ::: "memory"); }
    __builtin_amdgcn_s_barrier();
  }
#undef STAGE

  // ---- epilogue: two 128-row halves through LDS (stride EPS) ----
  const bool isQ = bn < 4096;
  const bool isV = bn >= 5120;
#pragma unroll 1
  for (int half = 0; half < 2; ++half) {
    __syncthreads();
    if (wrow == half) {
#pragma unroll
      for (int mi = 0; mi < 8; ++mi)
#pragma unroll
        for (int ni = 0; ni < 4; ++ni)
#pragma unroll
          for (int r = 0; r < 4; ++r)
            smem[(mi * 16 + quad * 4 + r) * EPS + wn + ni * 16 + lr] = (bf16_t)acc[mi][ni][r];
    }
    __syncthreads();
    const int growb = bm + half * 128;
    if (!isV) {  // ---- Q or K heads: RMSNorm + RoPE, write [h][s][128] ----
      const int r = tid >> 2, hh = (tid >> 1) & 1, hf = tid & 1;
      const int cb = bn + hh * 128;
      const float* nwp = isQ ? qnw : knw;
      const float osc = isQ ? QSCALE : 1.0f;
      bf16_t* outp = isQ ? (Qb + (long)(cb >> 7) * SEQL * HD)
                         : (Kb + (long)((cb - 4096) >> 7) * SEQL * HD);
      bf16x8 rowv[16];
#pragma unroll
      for (int j = 0; j < 16; ++j) rowv[j] = *(const bf16x8*)&smem[r * EPS + hh * 128 + j * 8];
      float ss = 0.f;
#pragma unroll
      for (int j = 0; j < 16; ++j)
#pragma unroll
        for (int e = 0; e < 8; ++e) { const float f = (float)rowv[j][e]; ss += f * f; }
      const float sc = rsqrtf(ss * (1.0f / 128.0f) + 1e-6f) * osc;
      const int p = pos[growb + r];
      const float* rp = rope + p * 128;
      bf16_t obuf[64];
#pragma unroll
      for (int g = 0; g < 8; ++g) {
#pragma unroll
        for (int e = 0; e < 8; ++e) {
          const int i = g * 8 + e;
          const float2 cs = *(const float2*)(rp + 2 * i);
          const float nlo = (float)rowv[i >> 3][i & 7] * sc * nwp[i];
          const float nhi = (float)rowv[8 + (i >> 3)][i & 7] * sc * nwp[64 + i];
          obuf[i] = (bf16_t)(hf ? (nhi * cs.x + nlo * cs.y) : (nlo * cs.x - nhi * cs.y));
        }
      }
      bf16_t* op = outp + (long)(growb + r) * HD + hf * 64;
#pragma unroll
      for (int g = 0; g < 8; ++g) *(bf16x8*)(op + g * 8) = *(const bf16x8*)&obuf[g * 8];
    } else {  // ---- V heads: transposed write [hk][d][s] ----
      const int d = tid & 127, q2 = tid >> 7;
      const int hh = q2 >> 1, shalf = q2 & 1;
      const int hv = ((bn - 5120) >> 7) + hh;
      bf16_t* vp = Vb + ((long)hv * HD + d) * SEQL + growb + shalf * 64;
#pragma unroll
      for (int grp = 0; grp < 8; ++grp) {
        bf16x8 tv;
#pragma unroll
        for (int e = 0; e < 8; ++e) tv[e] = smem[(shalf * 64 + grp * 8 + e) * EPS + hh * 128 + d];
        *(bf16x8*)(vp + grp * 8) = tv;
      }
    }
  }
}

// ---------------- plain NT GEMM (O-projection): C[M,N] = A @ B^T, fp32 out ---
template <typename CT>
__global__ __launch_bounds__(256, 3) void gemm_bt_kernel(const bf16_t* __restrict__ A,
                                                         const bf16_t* __restrict__ B,
                                                         CT* __restrict__ C,
                                                         int N, int K, int npanel) {
  __shared__ bf16_t lA[128 * 64];
  __shared__ bf16_t lB[128 * 64];
  const int tid = threadIdx.x;
  const int lin = blockIdx.x;
  const int xcd = lin & 7, idx = lin >> 3;
  const int bm = (idx & 15) * 128;
  const int bn = ((idx >> 4) + xcd * npanel) * 128;
  const int lane = tid & 63, wave = tid >> 6;
  const int wm = (wave >> 1) * 64, wn = (wave & 1) * 64;
  const int lr = lane & 15, quad = lane >> 4;

  f32x4 acc[4][4];
#pragma unroll
  for (int mi = 0; mi < 4; ++mi)
#pragma unroll
    for (int ni = 0; ni < 4; ++ni)
      acc[mi][ni] = (f32x4){0.f, 0.f, 0.f, 0.f};

  long soff[4];
#pragma unroll
  for (int c = 0; c < 4; ++c) {
    const int s = tid + 256 * c;
    soff[c] = (long)(s >> 3) * K + (((s & 7) ^ ((s >> 3) & 7)) << 3);
  }
  const bf16_t* Abase = A + (long)bm * K;
  const bf16_t* Bbase = B + (long)bn * K;

  for (int k0 = 0; k0 < K; k0 += 64) {
    __syncthreads();
#pragma unroll
    for (int c = 0; c < 4; ++c) {
      gl2lds16(Abase + soff[c] + k0, lA + (tid + 256 * c) * 8);
      gl2lds16(Bbase + soff[c] + k0, lB + (tid + 256 * c) * 8);
    }
    __syncthreads();
#pragma unroll
    for (int ks = 0; ks < 2; ++ks) {
      bf16x8 af[4], bfr[4];
#pragma unroll
      for (int mi = 0; mi < 4; ++mi)
        af[mi] = *(const bf16x8*)&lA[(wm + mi * 16 + lr) * 64 + ((((ks << 2) | quad) ^ (lr & 7)) << 3)];
#pragma unroll
      for (int ni = 0; ni < 4; ++ni)
        bfr[ni] = *(const bf16x8*)&lB[(wn + ni * 16 + lr) * 64 + ((((ks << 2) | quad) ^ (lr & 7)) << 3)];
#pragma unroll
      for (int mi = 0; mi < 4; ++mi)
#pragma unroll
        for (int ni = 0; ni < 4; ++ni)
          acc[mi][ni] = __builtin_amdgcn_mfma_f32_16x16x32_bf16(af[mi], bfr[ni], acc[mi][ni], 0, 0, 0);
    }
  }

#pragma unroll
  for (int mi = 0; mi < 4; ++mi) {
    const int row = bm + wm + mi * 16 + quad * 4;
#pragma unroll
    for (int ni = 0; ni < 4; ++ni) {
      const int col = bn + wn + ni * 16 + lr;
      CT* cp = C + (long)row * N + col;
#pragma unroll
      for (int r = 0; r < 4; ++r) cp[(long)r * N] = (CT)acc[mi][ni][r];
    }
  }
}

// ---------------- flash attention, block-diag causal, FIXED-RANGE softmax ----
#define CK 64
#define PSTR 72
__global__ __launch_bounds__(256) void attn_kernel(const bf16_t* __restrict__ Q,
                                                   const bf16_t* __restrict__ Kt,
                                                   const bf16_t* __restrict__ Vt,
                                                   bf16_t* __restrict__ O) {
  __shared__ bf16_t lK[CK * 128];    // [kk][d]
  __shared__ bf16_t lV[144 * CK];    // [d][kk]; rows 128..143 = ones (l trick)
  __shared__ bf16_t lP[128 * PSTR];  // [m][kk]
  const int lin = blockIdx.x;
  const int qb = (lin < 256) ? (3 - (lin & 1)) : (lin & 1);
  const int gh = (lin >> 1) & 127;
  const int h = gh & 31, g = gh >> 5;
  const int hk = h >> 2;
  const int tid = threadIdx.x, lane = tid & 63, wave = tid >> 6;
  const int lr = lane & 15, quad = lane >> 4;
  const int s_base = g * 512 + qb * 128;

  if (tid < 128) {
    bf16x8 one8;
#pragma unroll
    for (int j = 0; j < 8; ++j) one8[j] = (bf16_t)1.0f;
    *(bf16x8*)&lV[128 * CK + tid * 8] = one8;
  }

  bf16x8 qf[2][4];
  const bf16_t* Qp = Q + ((long)h * SEQL + s_base + wave * 32 + lr) * HD + quad * 8;
#pragma unroll
  for (int mi = 0; mi < 2; ++mi)
#pragma unroll
    for (int ks = 0; ks < 4; ++ks)
      qf[mi][ks] = *(const bf16x8*)(Qp + mi * 16 * HD + ks * 32);

  f32x4 oacc[2][9];
#pragma unroll
  for (int mi = 0; mi < 2; ++mi)
#pragma unroll
    for (int di = 0; di < 9; ++di) oacc[mi][di] = (f32x4){0.f, 0.f, 0.f, 0.f};

  const int nchunk = 2 * qb + 2;
  for (int c = 0; c < nchunk; ++c) {
    __syncthreads();
    {
      const bf16_t* Kg = Kt + ((long)hk * SEQL + g * 512 + c * CK) * HD;
      const bf16_t* Vg = Vt + (long)hk * HD * SEQL + g * 512 + c * CK;
#pragma unroll
      for (int cc = 0; cc < 4; ++cc) {
        const int i = tid + 256 * cc;
        gl2lds16(Kg + (long)(i >> 4) * HD + (i & 15) * 8, lK + i * 8);
        gl2lds16(Vg + (long)(i >> 3) * SEQL + (i & 7) * 8, lV + i * 8);
      }
    }
    __syncthreads();

    f32x4 sv[2][4];
#pragma unroll
    for (int mi = 0; mi < 2; ++mi)
#pragma unroll
      for (int ni = 0; ni < 4; ++ni) sv[mi][ni] = (f32x4){0.f, 0.f, 0.f, 0.f};
#pragma unroll
    for (int ks = 0; ks < 4; ++ks) {
#pragma unroll
      for (int ni = 0; ni < 4; ++ni) {
        const bf16x8 kf = *(const bf16x8*)&lK[(ni * 16 + lr) * 128 + ks * 32 + quad * 8];
        sv[0][ni] = __builtin_amdgcn_mfma_f32_16x16x32_bf16(qf[0][ks], kf, sv[0][ni], 0, 0, 0);
        sv[1][ni] = __builtin_amdgcn_mfma_f32_16x16x32_bf16(qf[1][ks], kf, sv[1][ni], 0, 0, 0);
      }
    }

#pragma unroll
    for (int mi = 0; mi < 2; ++mi)
#pragma unroll
      for (int ni = 0; ni < 4; ++ni)
#pragma unroll
        for (int r = 0; r < 4; ++r) {
          const int colseg = c * CK + ni * 16 + lr;
          const int rowseg = qb * 128 + wave * 32 + mi * 16 + quad * 4 + r;
          float p = exp2f(sv[mi][ni][r]);
          p = (colseg > rowseg) ? 0.f : p;
          lP[(wave * 32 + mi * 16 + quad * 4 + r) * PSTR + ni * 16 + lr] = (bf16_t)p;
        }
    __syncthreads();

#pragma unroll
    for (int ks = 0; ks < 2; ++ks) {
      const bf16x8 pf0 = *(const bf16x8*)&lP[(wave * 32 + lr) * PSTR + ks * 32 + quad * 8];
      const bf16x8 pf1 = *(const bf16x8*)&lP[(wave * 32 + 16 + lr) * PSTR + ks * 32 + quad * 8];
#pragma unroll
      for (int di = 0; di < 9; ++di) {
        const bf16x8 vfr = *(const bf16x8*)&lV[(di * 16 + lr) * CK + ks * 32 + quad * 8];
        oacc[0][di] = __builtin_amdgcn_mfma_f32_16x16x32_bf16(pf0, vfr, oacc[0][di], 0, 0, 0);
        oacc[1][di] = __builtin_amdgcn_mfma_f32_16x16x32_bf16(pf1, vfr, oacc[1][di], 0, 0, 0);
      }
    }
  }

#pragma unroll
  for (int mi = 0; mi < 2; ++mi)
#pragma unroll
    for (int r = 0; r < 4; ++r) {
      const float inv = 1.0f / oacc[mi][8][r];
      const int row = s_base + wave * 32 + mi * 16 + quad * 4 + r;
      bf16_t* opp = O + (long)row * DIMM + h * HD + lr;
#pragma unroll
      for (int di = 0; di < 8; ++di) opp[di * 16] = (bf16_t)(oacc[mi][di][r] * inv);
    }
}

// -----------------------------------------------------------------------------
extern "C" void kernel_launch(void* const* d_in, const int* in_sizes, int n_in,
                              void* d_out, int out_size, void* d_ws, size_t ws_size,
                              hipStream_t stream) {
  (void)in_sizes; (void)n_in; (void)out_size; (void)ws_size;
  const float* x    = (const float*)d_in[0];
  const float* wq   = (const float*)d_in[1];
  const float* wk   = (const float*)d_in[2];
  const float* wv   = (const float*)d_in[3];
  const float* wo   = (const float*)d_in[4];
  const float* qnw  = (const float*)d_in[5];
  const float* knw  = (const float*)d_in[6];
  const float* rope = (const float*)d_in[7];
  const int*   pos  = (const int*)d_in[8];
  float* out = (float*)d_out;

  char* ws = (char*)d_ws;
  size_t off = 0;
  auto alloc = [&](size_t b) { char* p = ws + off; off += (b + 255) & ~(size_t)255; return p; };
  bf16_t* xb    = (bf16_t*)alloc((size_t)SEQL * DIMM * 2);
  bf16_t* wqkvb = (bf16_t*)alloc((size_t)DIMM * DIMM * 2);
  alloc((size_t)NKV * HD * DIMM * 2);
  alloc((size_t)NKV * HD * DIMM * 2);
  bf16_t* wob   = (bf16_t*)alloc((size_t)DIMM * DIMM * 2);
  bf16_t* Qb    = (bf16_t*)alloc((size_t)NH * SEQL * HD * 2);
  bf16_t* Kb    = (bf16_t*)alloc((size_t)NKV * SEQL * HD * 2);
  bf16_t* Vb    = (bf16_t*)alloc((size_t)NKV * SEQL * HD * 2);
  bf16_t* attnb = xb;  // xb dead after QKV GEMM

  cvt5_kernel<<<dim3(12288), 256, 0, stream>>>(x, wq, wk, wv, wo, xb);
  gemm_qkv8<<<dim3(192), 512, 0, stream>>>(xb, wqkvb, qnw, knw, rope, pos, Qb, Kb, Vb);
  attn_kernel<<<dim3(512), 256, 0, stream>>>(Qb, Kb, Vb, attnb);
  gemm_bt_kernel<float><<<dim3(512), 256, 0, stream>>>(attnb, wob, out, DIMM, DIMM, 4);
}

// Round 5
// 439.998 us; speedup vs baseline: 1.2071x; 1.1940x over previous
//
#include <hip/hip_runtime.h>

typedef __bf16 bf16_t;
typedef __bf16 bf16x8 __attribute__((ext_vector_type(8)));
typedef __bf16 bf16x4 __attribute__((ext_vector_type(4)));
typedef float f32x4 __attribute__((ext_vector_type(4)));

#define SEQL 2048
#define DIMM 4096
#define NH 32
#define NKV 8
#define HD 128

__device__ __forceinline__ void gl2lds16(const void* g, void* l) {
  __builtin_amdgcn_global_load_lds((__attribute__((address_space(1))) void*)g,
                                   (__attribute__((address_space(3))) void*)l,
                                   16, 0, 0);
}

// ---------------- fused fp32 -> bf16 convert of all 5 tensors ----------------
__global__ __launch_bounds__(256) void cvt5_kernel(const float* __restrict__ s0,
                                                   const float* __restrict__ s1,
                                                   const float* __restrict__ s2,
                                                   const float* __restrict__ s3,
                                                   const float* __restrict__ s4,
                                                   bf16_t* __restrict__ dst) {
  const long base = (long)blockIdx.x * 4096;
  const float* s;
  long o;
  if (base < 8388608L)       { s = s0; o = base; }
  else if (base < 25165824L) { s = s1; o = base - 8388608L; }
  else if (base < 29360128L) { s = s2; o = base - 25165824L; }
  else if (base < 33554432L) { s = s3; o = base - 29360128L; }
  else                       { s = s4; o = base - 33554432L; }
  const long t4 = threadIdx.x * 4;
#pragma unroll
  for (int j = 0; j < 4; ++j) {
    const long e = t4 + j * 1024;
    float4 v = *(const float4*)(s + o + e);
    bf16x4 ov;
    ov[0] = (bf16_t)v.x; ov[1] = (bf16_t)v.y; ov[2] = (bf16_t)v.z; ov[3] = (bf16_t)v.w;
    *(bf16x4*)(dst + base + e) = ov;
  }
}

// ---------------- QKV GEMM, 128x384 tile, 8-wave deep-pipelined schedule -----
// Grid 256 = 16 m-tiles x 16 n-panels -> exactly 1 block/CU, no idle CUs.
// BK=32, 4-slot LDS ring: A 4x[128][32] (32KB) + B 4x[384][32] (96KB) = 128KB.
// Per tile: 2 phases {7|3 ds_read_b128 | 2 gl_lds for t+2 | barrier | lgkm(0) |
// 12 MFMA | barrier}; one counted vmcnt(4) per tile (never 0 in main loop).
// acc = 4x6 f32x4 = 96 regs; reg-light epilogue => fits the 256-reg/wave cap
// (512-thr block = 2 waves/EU always; round-2/3 spilled 45.7MB with acc=128).
#define BK2 32
#define EPSTR 392
#define QSCALE (0.08838834764831845f * 1.4426950408889634f)
__global__ __launch_bounds__(512, 2) void gemm_qkv8(const bf16_t* __restrict__ A,
                                                    const bf16_t* __restrict__ B,
                                                    const float* __restrict__ qnw,
                                                    const float* __restrict__ knw,
                                                    const float* __restrict__ rope,
                                                    const int* __restrict__ pos,
                                                    bf16_t* __restrict__ Qb,
                                                    bf16_t* __restrict__ Kb,
                                                    bf16_t* __restrict__ Vb) {
  __shared__ __align__(16) bf16_t smem[65536];  // 128 KiB
  const int K = DIMM;
  const int NT = K / BK2;  // 128 K-tiles
  const int tid = threadIdx.x;
  const int lin = blockIdx.x;  // 256 blocks
  const int xcd = lin & 7, idx = lin >> 3;
  const int bm = (idx & 15) * 128;
  const int bn = ((idx >> 4) + xcd * 2) * 384;  // 2 n-panels per XCD
  const int lane = tid & 63, wave = tid >> 6;
  const int wrow = wave >> 2, wcol = wave & 3;  // 2(M) x 4(N) waves
  const int wm = wrow * 64, wn = wcol * 96;     // per-wave 64x96 output
  const int lr = lane & 15, quad = lane >> 4;
  const int swz = (quad ^ ((lr >> 1) & 3)) << 3;  // read-side k-group swizzle

  // staging: A = 512 chunks (1/thread), B = 1536 chunks (3/thread).
  // chunk id: row=id>>2, kgrp=id&3; LDS dest linear (id*8 elems); global k
  // pre-swizzled so read-side XOR recovers k=quad*8.
  const int idA = tid;
  const long srcA = (long)(idA >> 2) * K + (((idA & 3) ^ ((idA >> 3) & 3)) << 3);
  const int dstA = idA * 8;
  long srcB[3]; int dstB[3];
#pragma unroll
  for (int c = 0; c < 3; ++c) {
    const int id = tid + 512 * c;
    srcB[c] = (long)(id >> 2) * K + (((id & 3) ^ ((id >> 3) & 3)) << 3);
    dstB[c] = id * 8;
  }
  const bf16_t* Abase = A + (long)bm * K;
  const bf16_t* Bbase = B + (long)bn * K;

  f32x4 acc[4][6];
#pragma unroll
  for (int mi = 0; mi < 4; ++mi)
#pragma unroll
    for (int ni = 0; ni < 6; ++ni)
      acc[mi][ni] = (f32x4){0.f, 0.f, 0.f, 0.f};

  // A slots: elems [0, 16384) step 4096; B slots: [16384, 65536) step 12288
#define STAGE_A(t)                                                               \
  do {                                                                           \
    const int sl_ = (t) & 3;                                                     \
    const long k0_ = (long)(t) * BK2;                                            \
    gl2lds16(Abase + srcA + k0_, smem + sl_ * 4096 + dstA);                      \
    gl2lds16(Bbase + srcB[0] + k0_, smem + 16384 + sl_ * 12288 + dstB[0]);       \
  } while (0)
#define STAGE_B(t)                                                               \
  do {                                                                           \
    const int sl_ = (t) & 3;                                                     \
    const long k0_ = (long)(t) * BK2;                                            \
    gl2lds16(Bbase + srcB[1] + k0_, smem + 16384 + sl_ * 12288 + dstB[1]);       \
    gl2lds16(Bbase + srcB[2] + k0_, smem + 16384 + sl_ * 12288 + dstB[2]);       \
  } while (0)

  // prologue: tiles 0 and 1 in flight; wait tile 0 only (tile 1 stays flying)
  STAGE_A(0); STAGE_B(0); STAGE_A(1); STAGE_B(1);
  asm volatile("s_waitcnt vmcnt(4)" ::: "memory");
  __builtin_amdgcn_s_barrier();

  for (int t = 0; t < NT; ++t) {
    const bf16_t* As = smem + (t & 3) * 4096;
    const bf16_t* Bs = smem + 16384 + (t & 3) * 12288;
    bf16x8 af[4], bfr[6];
    // ---- phase A: all 4 A-frags + first 3 B-frags -> 12 MFMA ----
#pragma unroll
    for (int mi = 0; mi < 4; ++mi)
      af[mi] = *(const bf16x8*)&As[(wm + mi * 16 + lr) * 32 + swz];
#pragma unroll
    for (int ni = 0; ni < 3; ++ni)
      bfr[ni] = *(const bf16x8*)&Bs[(wn + ni * 16 + lr) * 32 + swz];
    if (t + 2 < NT) STAGE_A(t + 2);
    __builtin_amdgcn_s_barrier();
    asm volatile("s_waitcnt lgkmcnt(0)" ::: "memory");
    __builtin_amdgcn_sched_barrier(0);
    __builtin_amdgcn_s_setprio(1);
#pragma unroll
    for (int mi = 0; mi < 4; ++mi)
#pragma unroll
      for (int ni = 0; ni < 3; ++ni)
        acc[mi][ni] = __builtin_amdgcn_mfma_f32_16x16x32_bf16(af[mi], bfr[ni], acc[mi][ni], 0, 0, 0);
    __builtin_amdgcn_s_setprio(0);
    __builtin_amdgcn_s_barrier();
    // ---- phase B: last 3 B-frags (A-frags reused) -> 12 MFMA ----
#pragma unroll
    for (int ni = 3; ni < 6; ++ni)
      bfr[ni] = *(const bf16x8*)&Bs[(wn + ni * 16 + lr) * 32 + swz];
    if (t + 2 < NT) STAGE_B(t + 2);
    __builtin_amdgcn_s_barrier();
    asm volatile("s_waitcnt lgkmcnt(0)" ::: "memory");
    __builtin_amdgcn_sched_barrier(0);
    __builtin_amdgcn_s_setprio(1);
#pragma unroll
    for (int mi = 0; mi < 4; ++mi)
#pragma unroll
      for (int ni = 3; ni < 6; ++ni)
        acc[mi][ni] = __builtin_amdgcn_mfma_f32_16x16x32_bf16(af[mi], bfr[ni], acc[mi][ni], 0, 0, 0);
    __builtin_amdgcn_s_setprio(0);
    // counted wait: tile t+1 landed; tile t+2's 4 loads stay in flight
    if (t + 2 < NT) { asm volatile("s_waitcnt vmcnt(4)" ::: "memory"); }
    else            { asm volatile("s_waitcnt vmcnt(0)" ::: "memory"); }
    __builtin_amdgcn_s_barrier();
  }
#undef STAGE_A
#undef STAGE_B

  // ---- epilogue: whole 128x384 C-tile -> LDS (stride EPSTR, 100KB) ----
  __syncthreads();  // full drain before overwriting the staging LDS
#pragma unroll
  for (int mi = 0; mi < 4; ++mi)
#pragma unroll
    for (int ni = 0; ni < 6; ++ni)
#pragma unroll
      for (int r = 0; r < 4; ++r)
        smem[(wm + mi * 16 + quad * 4 + r) * EPSTR + wn + ni * 16 + lr] = (bf16_t)acc[mi][ni][r];
  __syncthreads();

  // 3 heads per tile; pass 0: heads 0,1 (256 threads each); pass 1: head 2.
#pragma unroll 1
  for (int pass = 0; pass < 2; ++pass) {
    const int hh = (pass == 0) ? (tid >> 8) : 2;
    if (pass == 1 && tid >= 256) break;
    const int tl = tid & 255;
    const int col0 = bn + hh * 128;
    if (col0 < 5120) {  // ---- Q or K head: RMSNorm + RoPE, write [h][s][128] --
      const bool isQ = col0 < 4096;
      const int r = tl >> 1, hf = tl & 1;
      const bf16_t* rowp = smem + r * EPSTR + hh * 128;
      float ss = 0.f;
#pragma unroll
      for (int j = 0; j < 16; ++j) {
        const bf16x8 v = *(const bf16x8*)&rowp[j * 8];
#pragma unroll
        for (int e = 0; e < 8; ++e) { const float f = (float)v[e]; ss += f * f; }
      }
      const float sc = rsqrtf(ss * (1.0f / 128.0f) + 1e-6f) * (isQ ? QSCALE : 1.0f);
      const float* nwp = isQ ? qnw : knw;
      const int p = pos[bm + r];
      const float* rp = rope + p * 128;
      bf16_t* op = (isQ ? (Qb + (long)(col0 >> 7) * SEQL * HD)
                        : (Kb + (long)((col0 - 4096) >> 7) * SEQL * HD))
                   + (long)(bm + r) * HD + hf * 64;
#pragma unroll
      for (int g = 0; g < 8; ++g) {
        const bf16x8 lo = *(const bf16x8*)&rowp[g * 8];
        const bf16x8 hi = *(const bf16x8*)&rowp[64 + g * 8];
        bf16x8 ov;
#pragma unroll
        for (int e = 0; e < 8; ++e) {
          const int i = g * 8 + e;
          const float2 cs = *(const float2*)(rp + 2 * i);
          const float nlo = (float)lo[e] * sc * nwp[i];
          const float nhi = (float)hi[e] * sc * nwp[64 + i];
          ov[e] = (bf16_t)(hf ? (nhi * cs.x + nlo * cs.y) : (nlo * cs.x - nhi * cs.y));
        }
        *(bf16x8*)(op + g * 8) = ov;
      }
    } else {  // ---- V head: transposed write [hk][d][s] ----
      const int d = tl & 127, shalf = tl >> 7;
      const int hv = (col0 - 5120) >> 7;
      bf16_t* vp = Vb + ((long)hv * HD + d) * SEQL + bm + shalf * 64;
#pragma unroll
      for (int grp = 0; grp < 8; ++grp) {
        bf16x8 tv;
#pragma unroll
        for (int e = 0; e < 8; ++e)
          tv[e] = smem[(shalf * 64 + grp * 8 + e) * EPSTR + hh * 128 + d];
        *(bf16x8*)(vp + grp * 8) = tv;
      }
    }
  }
}

// ---------------- plain NT GEMM (O-projection): C[M,N] = A @ B^T, fp32 out ---
template <typename CT>
__global__ __launch_bounds__(256, 3) void gemm_bt_kernel(const bf16_t* __restrict__ A,
                                                         const bf16_t* __restrict__ B,
                                                         CT* __restrict__ C,
                                                         int N, int K, int npanel) {
  __shared__ bf16_t lA[128 * 64];
  __shared__ bf16_t lB[128 * 64];
  const int tid = threadIdx.x;
  const int lin = blockIdx.x;
  const int xcd = lin & 7, idx = lin >> 3;
  const int bm = (idx & 15) * 128;
  const int bn = ((idx >> 4) + xcd * npanel) * 128;
  const int lane = tid & 63, wave = tid >> 6;
  const int wm = (wave >> 1) * 64, wn = (wave & 1) * 64;
  const int lr = lane & 15, quad = lane >> 4;

  f32x4 acc[4][4];
#pragma unroll
  for (int mi = 0; mi < 4; ++mi)
#pragma unroll
    for (int ni = 0; ni < 4; ++ni)
      acc[mi][ni] = (f32x4){0.f, 0.f, 0.f, 0.f};

  long soff[4];
#pragma unroll
  for (int c = 0; c < 4; ++c) {
    const int s = tid + 256 * c;
    soff[c] = (long)(s >> 3) * K + (((s & 7) ^ ((s >> 3) & 7)) << 3);
  }
  const bf16_t* Abase = A + (long)bm * K;
  const bf16_t* Bbase = B + (long)bn * K;

  for (int k0 = 0; k0 < K; k0 += 64) {
    __syncthreads();
#pragma unroll
    for (int c = 0; c < 4; ++c) {
      gl2lds16(Abase + soff[c] + k0, lA + (tid + 256 * c) * 8);
      gl2lds16(Bbase + soff[c] + k0, lB + (tid + 256 * c) * 8);
    }
    __syncthreads();
#pragma unroll
    for (int ks = 0; ks < 2; ++ks) {
      bf16x8 af[4], bfr[4];
#pragma unroll
      for (int mi = 0; mi < 4; ++mi)
        af[mi] = *(const bf16x8*)&lA[(wm + mi * 16 + lr) * 64 + ((((ks << 2) | quad) ^ (lr & 7)) << 3)];
#pragma unroll
      for (int ni = 0; ni < 4; ++ni)
        bfr[ni] = *(const bf16x8*)&lB[(wn + ni * 16 + lr) * 64 + ((((ks << 2) | quad) ^ (lr & 7)) << 3)];
#pragma unroll
      for (int mi = 0; mi < 4; ++mi)
#pragma unroll
        for (int ni = 0; ni < 4; ++ni)
          acc[mi][ni] = __builtin_amdgcn_mfma_f32_16x16x32_bf16(af[mi], bfr[ni], acc[mi][ni], 0, 0, 0);
    }
  }

#pragma unroll
  for (int mi = 0; mi < 4; ++mi) {
    const int row = bm + wm + mi * 16 + quad * 4;
#pragma unroll
    for (int ni = 0; ni < 4; ++ni) {
      const int col = bn + wn + ni * 16 + lr;
      CT* cp = C + (long)row * N + col;
#pragma unroll
      for (int r = 0; r < 4; ++r) cp[(long)r * N] = (CT)acc[mi][ni][r];
    }
  }
}

// ---------------- flash attention, block-diag causal, FIXED-RANGE softmax ----
#define CK 64
#define PSTR 72
__global__ __launch_bounds__(256) void attn_kernel(const bf16_t* __restrict__ Q,
                                                   const bf16_t* __restrict__ Kt,
                                                   const bf16_t* __restrict__ Vt,
                                                   bf16_t* __restrict__ O) {
  __shared__ bf16_t lK[CK * 128];    // [kk][d]
  __shared__ bf16_t lV[144 * CK];    // [d][kk]; rows 128..143 = ones (l trick)
  __shared__ bf16_t lP[128 * PSTR];  // [m][kk]
  const int lin = blockIdx.x;
  const int qb = (lin < 256) ? (3 - (lin & 1)) : (lin & 1);
  const int gh = (lin >> 1) & 127;
  const int h = gh & 31, g = gh >> 5;
  const int hk = h >> 2;
  const int tid = threadIdx.x, lane = tid & 63, wave = tid >> 6;
  const int lr = lane & 15, quad = lane >> 4;
  const int s_base = g * 512 + qb * 128;

  if (tid < 128) {
    bf16x8 one8;
#pragma unroll
    for (int j = 0; j < 8; ++j) one8[j] = (bf16_t)1.0f;
    *(bf16x8*)&lV[128 * CK + tid * 8] = one8;
  }

  bf16x8 qf[2][4];
  const bf16_t* Qp = Q + ((long)h * SEQL + s_base + wave * 32 + lr) * HD + quad * 8;
#pragma unroll
  for (int mi = 0; mi < 2; ++mi)
#pragma unroll
    for (int ks = 0; ks < 4; ++ks)
      qf[mi][ks] = *(const bf16x8*)(Qp + mi * 16 * HD + ks * 32);

  f32x4 oacc[2][9];
#pragma unroll
  for (int mi = 0; mi < 2; ++mi)
#pragma unroll
    for (int di = 0; di < 9; ++di) oacc[mi][di] = (f32x4){0.f, 0.f, 0.f, 0.f};

  const int nchunk = 2 * qb + 2;
  for (int c = 0; c < nchunk; ++c) {
    __syncthreads();
    {
      const bf16_t* Kg = Kt + ((long)hk * SEQL + g * 512 + c * CK) * HD;
      const bf16_t* Vg = Vt + (long)hk * HD * SEQL + g * 512 + c * CK;
#pragma unroll
      for (int cc = 0; cc < 4; ++cc) {
        const int i = tid + 256 * cc;
        gl2lds16(Kg + (long)(i >> 4) * HD + (i & 15) * 8, lK + i * 8);
        gl2lds16(Vg + (long)(i >> 3) * SEQL + (i & 7) * 8, lV + i * 8);
      }
    }
    __syncthreads();

    f32x4 sv[2][4];
#pragma unroll
    for (int mi = 0; mi < 2; ++mi)
#pragma unroll
      for (int ni = 0; ni < 4; ++ni) sv[mi][ni] = (f32x4){0.f, 0.f, 0.f, 0.f};
#pragma unroll
    for (int ks = 0; ks < 4; ++ks) {
#pragma unroll
      for (int ni = 0; ni < 4; ++ni) {
        const bf16x8 kf = *(const bf16x8*)&lK[(ni * 16 + lr) * 128 + ks * 32 + quad * 8];
        sv[0][ni] = __builtin_amdgcn_mfma_f32_16x16x32_bf16(qf[0][ks], kf, sv[0][ni], 0, 0, 0);
        sv[1][ni] = __builtin_amdgcn_mfma_f32_16x16x32_bf16(qf[1][ks], kf, sv[1][ni], 0, 0, 0);
      }
    }

#pragma unroll
    for (int mi = 0; mi < 2; ++mi)
#pragma unroll
      for (int ni = 0; ni < 4; ++ni)
#pragma unroll
        for (int r = 0; r < 4; ++r) {
          const int colseg = c * CK + ni * 16 + lr;
          const int rowseg = qb * 128 + wave * 32 + mi * 16 + quad * 4 + r;
          float p = exp2f(sv[mi][ni][r]);
          p = (colseg > rowseg) ? 0.f : p;
          lP[(wave * 32 + mi * 16 + quad * 4 + r) * PSTR + ni * 16 + lr] = (bf16_t)p;
        }
    __syncthreads();

#pragma unroll
    for (int ks = 0; ks < 2; ++ks) {
      const bf16x8 pf0 = *(const bf16x8*)&lP[(wave * 32 + lr) * PSTR + ks * 32 + quad * 8];
      const bf16x8 pf1 = *(const bf16x8*)&lP[(wave * 32 + 16 + lr) * PSTR + ks * 32 + quad * 8];
#pragma unroll
      for (int di = 0; di < 9; ++di) {
        const bf16x8 vfr = *(const bf16x8*)&lV[(di * 16 + lr) * CK + ks * 32 + quad * 8];
        oacc[0][di] = __builtin_amdgcn_mfma_f32_16x16x32_bf16(pf0, vfr, oacc[0][di], 0, 0, 0);
        oacc[1][di] = __builtin_amdgcn_mfma_f32_16x16x32_bf16(pf1, vfr, oacc[1][di], 0, 0, 0);
      }
    }
  }

#pragma unroll
  for (int mi = 0; mi < 2; ++mi)
#pragma unroll
    for (int r = 0; r < 4; ++r) {
      const float inv = 1.0f / oacc[mi][8][r];
      const int row = s_base + wave * 32 + mi * 16 + quad * 4 + r;
      bf16_t* opp = O + (long)row * DIMM + h * HD + lr;
#pragma unroll
      for (int di = 0; di < 8; ++di) opp[di * 16] = (bf16_t)(oacc[mi][di][r] * inv);
    }
}

// -----------------------------------------------------------------------------
extern "C" void kernel_launch(void* const* d_in, const int* in_sizes, int n_in,
                              void* d_out, int out_size, void* d_ws, size_t ws_size,
                              hipStream_t stream) {
  (void)in_sizes; (void)n_in; (void)out_size; (void)ws_size;
  const float* x    = (const float*)d_in[0];
  const float* wq   = (const float*)d_in[1];
  const float* wk   = (const float*)d_in[2];
  const float* wv   = (const float*)d_in[3];
  const float* wo   = (const float*)d_in[4];
  const float* qnw  = (const float*)d_in[5];
  const float* knw  = (const float*)d_in[6];
  const float* rope = (const float*)d_in[7];
  const int*   pos  = (const int*)d_in[8];
  float* out = (float*)d_out;

  char* ws = (char*)d_ws;
  size_t off = 0;
  auto alloc = [&](size_t b) { char* p = ws + off; off += (b + 255) & ~(size_t)255; return p; };
  bf16_t* xb    = (bf16_t*)alloc((size_t)SEQL * DIMM * 2);
  bf16_t* wqkvb = (bf16_t*)alloc((size_t)DIMM * DIMM * 2);
  alloc((size_t)NKV * HD * DIMM * 2);
  alloc((size_t)NKV * HD * DIMM * 2);
  bf16_t* wob   = (bf16_t*)alloc((size_t)DIMM * DIMM * 2);
  bf16_t* Qb    = (bf16_t*)alloc((size_t)NH * SEQL * HD * 2);
  bf16_t* Kb    = (bf16_t*)alloc((size_t)NKV * SEQL * HD * 2);
  bf16_t* Vb    = (bf16_t*)alloc((size_t)NKV * SEQL * HD * 2);
  bf16_t* attnb = xb;  // xb dead after QKV GEMM

  cvt5_kernel<<<dim3(12288), 256, 0, stream>>>(x, wq, wk, wv, wo, xb);
  gemm_qkv8<<<dim3(256), 512, 0, stream>>>(xb, wqkvb, qnw, knw, rope, pos, Qb, Kb, Vb);
  attn_kernel<<<dim3(512), 256, 0, stream>>>(Qb, Kb, Vb, attnb);
  gemm_bt_kernel<float><<<dim3(512), 256, 0, stream>>>(attnb, wob, out, DIMM, DIMM, 4);
}